// Round 1
// baseline (489.746 us; speedup 1.0000x reference)
//
#include <hip/hip_runtime.h>
#include <hip/hip_bf16.h>

#define B_   4
#define C_   256
#define HW_  4096
#define NH_  4
#define HD_  64
#define GR_  32
#define CPG_ 8
#define EPS_ 1e-5f
#define SCALE_ 0.0625f           // 1/sqrt(C) = 1/16
#define RSQRT2_ 0.70710678118654752f

typedef short bf16x8 __attribute__((ext_vector_type(8)));
typedef float f32x4  __attribute__((ext_vector_type(4)));
typedef unsigned short u16x4 __attribute__((ext_vector_type(4)));

__device__ __forceinline__ float bf2f(unsigned short u) {
  unsigned int x = ((unsigned int)u) << 16;
  float f; __builtin_memcpy(&f, &x, 4); return f;
}
__device__ __forceinline__ unsigned short f2bf(float f) {
  unsigned int x; __builtin_memcpy(&x, &f, 4);
  x = x + 0x7FFFu + ((x >> 16) & 1u);
  return (unsigned short)(x >> 16);
}

// ---------------- K0: group-norm stats (mean, rstd) per (b, group) ----------------
__global__ __launch_bounds__(256) void gn_stats(const float* __restrict__ x,
                                                float* __restrict__ stats) {
  int bg = blockIdx.x;  // b*32 + g ; group = 8 consecutive channels
  const float4* p = (const float4*)(x + (size_t)bg * (CPG_ * HW_));
  float s = 0.f, ss = 0.f;
  for (int i = threadIdx.x; i < (CPG_ * HW_ / 4); i += 256) {
    float4 v = p[i];
    s  += v.x + v.y + v.z + v.w;
    ss += v.x * v.x + v.y * v.y + v.z * v.z + v.w * v.w;
  }
  #pragma unroll
  for (int off = 32; off > 0; off >>= 1) {
    s  += __shfl_down(s, off, 64);
    ss += __shfl_down(ss, off, 64);
  }
  __shared__ float rs[4], rss[4];
  int wv = threadIdx.x >> 6;
  if ((threadIdx.x & 63) == 0) { rs[wv] = s; rss[wv] = ss; }
  __syncthreads();
  if (threadIdx.x == 0) {
    float S = rs[0] + rs[1] + rs[2] + rs[3];
    float SS = rss[0] + rss[1] + rss[2] + rss[3];
    float mean = S * (1.f / (CPG_ * HW_));
    float var = SS * (1.f / (CPG_ * HW_)) - mean * mean;
    stats[bg * 2 + 0] = mean;
    stats[bg * 2 + 1] = rsqrtf(var + EPS_);
  }
}

// ---------------- K1: normalize + gamma/beta -> bf16 ----------------
__global__ __launch_bounds__(256) void gn_apply(const float* __restrict__ x,
                                                const float* __restrict__ stats,
                                                const float* __restrict__ gamma,
                                                const float* __restrict__ beta,
                                                unsigned short* __restrict__ xn) {
  int i = blockIdx.x * 256 + threadIdx.x;   // float4 index, total 1,048,576
  int c = (i >> 10) & (C_ - 1);             // HW/4 = 1024 float4 per channel row
  int b = i >> 18;                          // C*HW/4 = 2^18
  int bg = b * GR_ + (c >> 3);
  float mean = stats[bg * 2], rstd = stats[bg * 2 + 1];
  float a = rstd * gamma[c];
  float bb = beta[c] - mean * a;
  float4 v = ((const float4*)x)[i];
  u16x4 o;
  o[0] = f2bf(v.x * a + bb);
  o[1] = f2bf(v.y * a + bb);
  o[2] = f2bf(v.z * a + bb);
  o[3] = f2bf(v.w * a + bb);
  ((u16x4*)xn)[i] = o;
}

// ---------------- K2: QKV projection GEMM (bf16 MFMA) ----------------
// C[o][p] = sum_c W[o][c] * XN[c][p] + bias[o]   (per batch)
__global__ __launch_bounds__(256) void gemm_qkv(const float* __restrict__ w,
                                                const float* __restrict__ bias,
                                                const unsigned short* __restrict__ xn,
                                                unsigned short* __restrict__ qkv) {
  int nt0 = blockIdx.x * 64;   // p tile
  int mt0 = blockIdx.y * 64;   // o tile
  int b   = blockIdx.z;
  int lane = threadIdx.x & 63, wv = threadIdx.x >> 6;
  int cl = lane & 15, g = lane >> 4;
  int orow = mt0 + wv * 16;

  f32x4 z = {0.f, 0.f, 0.f, 0.f};
  f32x4 acc[4] = {z, z, z, z};

  const float* wrow = w + (size_t)(orow + cl) * C_;
  const unsigned short* xb = xn + (size_t)b * C_ * HW_;

  for (int kc = 0; kc < C_; kc += 32) {
    bf16x8 af;
    float4 a0 = *(const float4*)(wrow + kc + g * 8);
    float4 a1 = *(const float4*)(wrow + kc + g * 8 + 4);
    af[0] = (short)f2bf(a0.x); af[1] = (short)f2bf(a0.y);
    af[2] = (short)f2bf(a0.z); af[3] = (short)f2bf(a0.w);
    af[4] = (short)f2bf(a1.x); af[5] = (short)f2bf(a1.y);
    af[6] = (short)f2bf(a1.z); af[7] = (short)f2bf(a1.w);
    #pragma unroll
    for (int nt = 0; nt < 4; ++nt) {
      bf16x8 bf;
      const unsigned short* xp = xb + (size_t)(kc + g * 8) * HW_ + nt0 + nt * 16 + cl;
      #pragma unroll
      for (int j = 0; j < 8; ++j) bf[j] = (short)xp[(size_t)j * HW_];
      acc[nt] = __builtin_amdgcn_mfma_f32_16x16x32_bf16(af, bf, acc[nt], 0, 0, 0);
    }
  }
  unsigned short* qb = qkv + (size_t)b * 768 * HW_;
  #pragma unroll
  for (int r = 0; r < 4; ++r) {
    int o = orow + g * 4 + r;
    float bv = bias[o];
    #pragma unroll
    for (int nt = 0; nt < 4; ++nt) {
      int p = nt0 + nt * 16 + cl;
      qb[(size_t)o * HW_ + p] = f2bf(acc[nt][r] + bv);
    }
  }
}

// ---------------- K3: flash attention (bf16 MFMA, online softmax) ----------------
// qkv channel layout per head: [h*192 + (q:0..63 | k:64..127 | v:128..191)]
__global__ __launch_bounds__(256) void flash_attn(const unsigned short* __restrict__ qkv,
                                                  unsigned short* __restrict__ attn) {
  int qt = blockIdx.x;   // 0..63 query tiles of 64
  int bh = blockIdx.y;   // 0..15
  int b = bh >> 2, h = bh & 3;
  int lane = threadIdx.x & 63, wv = threadIdx.x >> 6;
  int cl = lane & 15, g = lane >> 4;

  const unsigned short* qbase = qkv + ((size_t)b * 768 + h * 192) * HW_;
  const unsigned short* kbase = qkv + ((size_t)b * 768 + h * 192 + 64) * HW_;
  const unsigned short* vbase = qkv + ((size_t)b * 768 + h * 192 + 128) * HW_;

  __shared__ unsigned short plds[4][64 * 16];  // per-wave P^T buffer [k][q]
  unsigned short* pw = plds[wv];

  // Q A-fragments (fixed for whole kernel): A[m=q][k=d]
  int qpix = qt * 64 + wv * 16 + cl;
  bf16x8 qf[2];
  #pragma unroll
  for (int ks = 0; ks < 2; ++ks)
    #pragma unroll
    for (int j = 0; j < 8; ++j)
      qf[ks][j] = (short)qbase[(size_t)(ks * 32 + g * 8 + j) * HW_ + qpix];

  f32x4 z = {0.f, 0.f, 0.f, 0.f};
  f32x4 oacc[4] = {z, z, z, z};
  float m_r[4] = {-__builtin_inff(), -__builtin_inff(), -__builtin_inff(), -__builtin_inff()};
  float l_r[4] = {0.f, 0.f, 0.f, 0.f};

  for (int kt = 0; kt < HW_; kt += 64) {
    // ---- S = Q^T K : D[q][key], B[k=d][n=key]
    f32x4 sacc[4] = {z, z, z, z};
    #pragma unroll
    for (int nt = 0; nt < 4; ++nt) {
      #pragma unroll
      for (int ks = 0; ks < 2; ++ks) {
        bf16x8 kf;
        const unsigned short* kp = kbase + (size_t)(ks * 32 + g * 8) * HW_ + kt + nt * 16 + cl;
        #pragma unroll
        for (int j = 0; j < 8; ++j) kf[j] = (short)kp[(size_t)j * HW_];
        sacc[nt] = __builtin_amdgcn_mfma_f32_16x16x32_bf16(qf[ks], kf, sacc[nt], 0, 0, 0);
      }
    }
    #pragma unroll
    for (int nt = 0; nt < 4; ++nt) sacc[nt] *= SCALE_;

    // ---- online softmax; row q = g*4+r lives on the 16 consecutive lanes of group g
    float scale[4];
    #pragma unroll
    for (int r = 0; r < 4; ++r) {
      float mx = fmaxf(fmaxf(sacc[0][r], sacc[1][r]), fmaxf(sacc[2][r], sacc[3][r]));
      #pragma unroll
      for (int off = 1; off < 16; off <<= 1) mx = fmaxf(mx, __shfl_xor(mx, off, 64));
      float mn = fmaxf(m_r[r], mx);
      float sc = __expf(m_r[r] - mn);
      m_r[r] = mn;
      scale[r] = sc;
      float rs = 0.f;
      #pragma unroll
      for (int nt = 0; nt < 4; ++nt) {
        float p = __expf(sacc[nt][r] - mn);
        sacc[nt][r] = p;
        rs += p;
      }
      #pragma unroll
      for (int off = 1; off < 16; off <<= 1) rs += __shfl_xor(rs, off, 64);
      l_r[r] = l_r[r] * sc + rs;
    }
    #pragma unroll
    for (int dt = 0; dt < 4; ++dt) {
      f32x4 o = oacc[dt];
      o[0] *= scale[0]; o[1] *= scale[1]; o[2] *= scale[2]; o[3] *= scale[3];
      oacc[dt] = o;
    }

    // ---- P -> bf16 -> per-wave LDS transpose [key_local][q_local]
    #pragma unroll
    for (int nt = 0; nt < 4; ++nt) {
      u16x4 pk;
      pk[0] = f2bf(sacc[nt][0]); pk[1] = f2bf(sacc[nt][1]);
      pk[2] = f2bf(sacc[nt][2]); pk[3] = f2bf(sacc[nt][3]);
      *(u16x4*)&pw[(nt * 16 + cl) * 16 + g * 4] = pk;  // rows k=nt*16+cl, cols q=g*4..+3
    }
    // P A-fragments: A[m=q][k=key_local]
    bf16x8 paf[2];
    #pragma unroll
    for (int ks = 0; ks < 2; ++ks)
      #pragma unroll
      for (int j = 0; j < 8; ++j)
        paf[ks][j] = (short)pw[(ks * 32 + g * 8 + j) * 16 + cl];

    // ---- O += P V^T : B[k=key][n=dout] ; key-dim contiguous in global => 16B loads
    #pragma unroll
    for (int dt = 0; dt < 4; ++dt) {
      #pragma unroll
      for (int ks = 0; ks < 2; ++ks) {
        bf16x8 vf = *(const bf16x8*)(vbase + (size_t)(dt * 16 + cl) * HW_ + kt + ks * 32 + g * 8);
        oacc[dt] = __builtin_amdgcn_mfma_f32_16x16x32_bf16(paf[ks], vf, oacc[dt], 0, 0, 0);
      }
    }
  }

  // ---- epilogue: attn[b][h*64+d][p] = O[q][d] / l[q]
  unsigned short* ab = attn + ((size_t)b * C_ + h * HD_) * HW_;
  #pragma unroll
  for (int dt = 0; dt < 4; ++dt) {
    int d = dt * 16 + cl;
    #pragma unroll
    for (int r = 0; r < 4; ++r) {
      int p = qt * 64 + wv * 16 + g * 4 + r;
      ab[(size_t)d * HW_ + p] = f2bf(oacc[dt][r] / l_r[r]);
    }
  }
}

// ---------------- K4: out projection + bias + residual + /sqrt(2) ----------------
__global__ __launch_bounds__(256) void gemm_out(const float* __restrict__ w,
                                                const float* __restrict__ bias,
                                                const unsigned short* __restrict__ attn,
                                                const float* __restrict__ x,
                                                float* __restrict__ out) {
  int nt0 = blockIdx.x * 64;
  int mt0 = blockIdx.y * 64;
  int b   = blockIdx.z;
  int lane = threadIdx.x & 63, wv = threadIdx.x >> 6;
  int cl = lane & 15, g = lane >> 4;
  int orow = mt0 + wv * 16;

  f32x4 z = {0.f, 0.f, 0.f, 0.f};
  f32x4 acc[4] = {z, z, z, z};
  const float* wrow = w + (size_t)(orow + cl) * C_;
  const unsigned short* ab = attn + (size_t)b * C_ * HW_;

  for (int kc = 0; kc < C_; kc += 32) {
    bf16x8 af;
    float4 a0 = *(const float4*)(wrow + kc + g * 8);
    float4 a1 = *(const float4*)(wrow + kc + g * 8 + 4);
    af[0] = (short)f2bf(a0.x); af[1] = (short)f2bf(a0.y);
    af[2] = (short)f2bf(a0.z); af[3] = (short)f2bf(a0.w);
    af[4] = (short)f2bf(a1.x); af[5] = (short)f2bf(a1.y);
    af[6] = (short)f2bf(a1.z); af[7] = (short)f2bf(a1.w);
    #pragma unroll
    for (int nt = 0; nt < 4; ++nt) {
      bf16x8 bf;
      const unsigned short* xp = ab + (size_t)(kc + g * 8) * HW_ + nt0 + nt * 16 + cl;
      #pragma unroll
      for (int j = 0; j < 8; ++j) bf[j] = (short)xp[(size_t)j * HW_];
      acc[nt] = __builtin_amdgcn_mfma_f32_16x16x32_bf16(af, bf, acc[nt], 0, 0, 0);
    }
  }
  const float* xb = x + (size_t)b * C_ * HW_;
  float* ob = out + (size_t)b * C_ * HW_;
  #pragma unroll
  for (int r = 0; r < 4; ++r) {
    int o = orow + g * 4 + r;
    float bv = bias[o];
    #pragma unroll
    for (int nt = 0; nt < 4; ++nt) {
      int p = nt0 + nt * 16 + cl;
      size_t idx = (size_t)o * HW_ + p;
      ob[idx] = (acc[nt][r] + bv + xb[idx]) * RSQRT2_;
    }
  }
}

extern "C" void kernel_launch(void* const* d_in, const int* in_sizes, int n_in,
                              void* d_out, int out_size, void* d_ws, size_t ws_size,
                              hipStream_t stream) {
  const float* x     = (const float*)d_in[0];
  const float* gamma = (const float*)d_in[1];
  const float* beta  = (const float*)d_in[2];
  const float* w_qkv = (const float*)d_in[3];
  const float* b_qkv = (const float*)d_in[4];
  const float* w_out = (const float*)d_in[5];
  const float* b_out = (const float*)d_in[6];
  float* out = (float*)d_out;

  char* ws = (char*)d_ws;
  float* stats          = (float*)ws;                                   // 1 KB
  unsigned short* xn    = (unsigned short*)(ws + 1024);                 // 8.39 MB
  unsigned short* qkv   = (unsigned short*)(ws + 1024 + 8388608);       // 25.2 MB
  unsigned short* attnb = (unsigned short*)(ws + 1024 + 8388608 + 25165824); // 8.39 MB

  gn_stats<<<dim3(128), dim3(256), 0, stream>>>(x, stats);
  gn_apply<<<dim3(4096), dim3(256), 0, stream>>>(x, stats, gamma, beta, xn);
  gemm_qkv<<<dim3(64, 12, 4), dim3(256), 0, stream>>>(w_qkv, b_qkv, xn, qkv);
  flash_attn<<<dim3(64, 16), dim3(256), 0, stream>>>(qkv, attnb);
  gemm_out<<<dim3(64, 4, 4), dim3(256), 0, stream>>>(w_out, b_out, attnb, x, out);
}